// Round 4
// baseline (613.136 us; speedup 1.0000x reference)
//
#include <hip/hip_runtime.h>

// ActorCritic fused: LSTM scan (B=1024,T=256,F=128,H=128) + MLP heads.
// R4: split input projection out of the scan.
//   k1 xg_gemm (512 blocks, full chip): xg = f16(x @ Wx), stored in MFMA
//      C-fragment order in d_ws (256 MiB).
//   k2 ac_scan (64 blocks): recurrence with K=128 (h @ Wh only), z initialized
//      from prefetched xg fragments; direct b16 h-writes; heads fused.
// Fallback to R3 monolithic kernel when ws_size < 256 MiB.

typedef _Float16 f16x8 __attribute__((ext_vector_type(8)));
typedef _Float16 f16x4 __attribute__((ext_vector_type(4)));
typedef float    f32x4 __attribute__((ext_vector_type(4)));

#define NLOG2E (-1.4426950408889634f)

__device__ __forceinline__ float rcpf(float x) { return __builtin_amdgcn_rcpf(x); }
__device__ __forceinline__ float ex2(float x)  { return __builtin_amdgcn_exp2f(x); }
__device__ __forceinline__ float dpp_swap1(float x) {
    return __builtin_bit_cast(float,
        __builtin_amdgcn_mov_dpp(__builtin_bit_cast(int, x), 0xB1, 0xF, 0xF, true));
}

// ============================ kernel 1: xg GEMM ============================
// grid 512: block = (blk = b&63 -> batch rows blk*16..+16, tq = b>>6 -> 32 t's)
__global__ __launch_bounds__(512, 2)
void xg_gemm(const float* __restrict__ hin, const float* __restrict__ Wx,
             _Float16* __restrict__ xg)
{
    __shared__ f16x8 As[2][256];            // 2 x 4 KB, double-buffered
    const int tid  = threadIdx.x;
    const int lane = tid & 63;
    const int wv   = tid >> 6;
    const int m16  = lane & 15;
    const int q    = lane >> 4;
    const int blk  = blockIdx.x & 63;
    const int tq   = blockIdx.x >> 6;       // 0..7 (32 t's each)
    const int r0   = blk << 4;
    const int ncol = (wv << 4) + m16;

    f16x8 bwx[4][4];
    #pragma unroll
    for (int kt = 0; kt < 4; ++kt)
        #pragma unroll
        for (int s = 0; s < 4; ++s) {
            f16x8 v;
            #pragma unroll
            for (int j = 0; j < 8; ++j) {
                const int k = (kt << 5) + (q << 3) + j;       // 0..127
                v[j] = (_Float16)Wx[k * 512 + s * 128 + ncol];
            }
            bwx[s][kt] = v;
        }

    const int xc  = tid >> 1, xh = tid & 1;
    const int xm  = xc & 15;
    const int xk0 = ((xc >> 6) << 5) + (((xc >> 4) & 3) << 3) + (xh << 2);
    const float* pxb = hin + (size_t)(r0 + xm) * 256 * 128 + xk0;

    for (int ti = 0; ti < 32; ++ti) {
        const int t = (tq << 5) + ti;
        // stage x_t into As[ti&1] (fragment order, conflict-free b64)
        {
            const float4 x0 = *(const float4*)(pxb + (size_t)t * 128);
            f16x4 pk;
            pk[0] = (_Float16)x0.x; pk[1] = (_Float16)x0.y;
            pk[2] = (_Float16)x0.z; pk[3] = (_Float16)x0.w;
            *(f16x4*)((_Float16*)&As[ti & 1][0] + xc * 8 + xh * 4) = pk;
        }
        __syncthreads();
        f16x8 af[4];
        #pragma unroll
        for (int kt = 0; kt < 4; ++kt) af[kt] = As[ti & 1][(kt << 6) + lane];

        _Float16* outp = xg + (((size_t)t * 64 + blk) * 8 + wv) * 1024 + lane * 4;
        #pragma unroll
        for (int s = 0; s < 4; ++s) {
            f32x4 z = {0.f, 0.f, 0.f, 0.f};
            #pragma unroll
            for (int kt = 0; kt < 4; ++kt)
                z = __builtin_amdgcn_mfma_f32_16x16x32_f16(af[kt], bwx[s][kt], z, 0, 0, 0);
            f16x4 o;
            o[0] = (_Float16)z[0]; o[1] = (_Float16)z[1];
            o[2] = (_Float16)z[2]; o[3] = (_Float16)z[3];
            *(f16x4*)(outp + s * 256) = o;
        }
    }
}

// ============================ kernel 2: scan ===============================
__global__ __launch_bounds__(512, 2)
void ac_scan(const _Float16* __restrict__ xg,
             const float* __restrict__ Wh, const float* __restrict__ bh,
             const float* __restrict__ Wa1, const float* __restrict__ ba1,
             const float* __restrict__ Wa2, const float* __restrict__ ba2,
             const float* __restrict__ Wa3, const float* __restrict__ ba3,
             const float* __restrict__ logstd,
             const float* __restrict__ Wc1, const float* __restrict__ bc1,
             const float* __restrict__ Wc2, const float* __restrict__ bc2,
             const float* __restrict__ Wc3, const float* __restrict__ bc3,
             float* __restrict__ out)
{
    constexpr int T = 256, F = 128;

    __shared__ f16x8 Abuf[2][256];          // h-only A tiles: 2 x 4 KB
    __shared__ float xf[16][F + 1];
    __shared__ float hb[2][16][257];

    const int tid  = threadIdx.x;
    const int lane = tid & 63;
    const int wv   = tid >> 6;
    const int m16  = lane & 15;
    const int q    = lane >> 4;
    const int blk  = blockIdx.x;
    const int r0   = blk << 4;
    const int ncol = (wv << 4) + m16;

    // Wh B-fragments (K=128): 64 VGPRs
    f16x8 bwh[4][4];
    #pragma unroll
    for (int kt = 0; kt < 4; ++kt)
        #pragma unroll
        for (int s = 0; s < 4; ++s) {
            f16x8 v;
            #pragma unroll
            for (int j = 0; j < 8; ++j) {
                const int k = (kt << 5) + (q << 3) + j;       // 0..127
                v[j] = (_Float16)Wh[k * 512 + s * 128 + ncol];
            }
            bwh[s][kt] = v;
        }
    const float nbi = NLOG2E * bh[0 * 128 + ncol];
    const float nbf = NLOG2E * bh[1 * 128 + ncol];
    const float nbg = 2.0f * NLOG2E * bh[2 * 128 + ncol];
    const float nbo = NLOG2E * bh[3 * 128 + ncol];

    // h-write target (direct b16): cell (row q*4+g, k = ncol)
    const int hch = ((ncol >> 5) << 6) + (((ncol >> 3) & 3) << 4);
    _Float16* hw0 = (_Float16*)&Abuf[0][0] + (hch + (q << 2)) * 8 + (ncol & 7);
    _Float16* hw1 = (_Float16*)&Abuf[1][0] + (hch + (q << 2)) * 8 + (ncol & 7);

    // zero h_0 tile
    ((f16x4*)&Abuf[0][0])[tid] = f16x4{};

    // xg fragment pointer (uint2 units): lane's f16x4 per section
    const uint2* xp = (const uint2*)xg + ((size_t)blk * 8 + wv) * 256 + lane;
    const size_t XSTRIDE = 131072;          // uint2 per t

    uint2 xc0 = xp[0], xc1 = xp[64], xc2 = xp[128], xc3 = xp[192];
    xp += XSTRIDE;

    f32x4 cst = {0.f, 0.f, 0.f, 0.f};
    f32x4 hlast;

    __syncthreads();

    for (int t = 0; t < T; ++t) {
        // prefetch next step's xg fragments
        uint2 xn0 = xc0, xn1 = xc1, xn2 = xc2, xn3 = xc3;
        if (t + 1 < T) {
            xn0 = xp[0]; xn1 = xp[64]; xn2 = xp[128]; xn3 = xp[192];
            xp += XSTRIDE;
        }

        // z init = xg fragment (f16 -> f32)
        const f16x4 v0 = __builtin_bit_cast(f16x4, xc0);
        const f16x4 v1 = __builtin_bit_cast(f16x4, xc1);
        const f16x4 v2 = __builtin_bit_cast(f16x4, xc2);
        const f16x4 v3 = __builtin_bit_cast(f16x4, xc3);
        f32x4 z0 = {(float)v0[0], (float)v0[1], (float)v0[2], (float)v0[3]};
        f32x4 z1 = {(float)v1[0], (float)v1[1], (float)v1[2], (float)v1[3]};
        f32x4 z2 = {(float)v2[0], (float)v2[1], (float)v2[2], (float)v2[3]};
        f32x4 z3 = {(float)v3[0], (float)v3[1], (float)v3[2], (float)v3[3]};

        // MFMA: z += h @ Wh   (K=128)
        const f16x8* Ab = &Abuf[t & 1][0];
        f16x8 af[4];
        #pragma unroll
        for (int kt = 0; kt < 4; ++kt) af[kt] = Ab[(kt << 6) + lane];
        #pragma unroll
        for (int kt = 0; kt < 4; ++kt) {
            z0 = __builtin_amdgcn_mfma_f32_16x16x32_f16(af[kt], bwh[0][kt], z0, 0, 0, 0);
            z1 = __builtin_amdgcn_mfma_f32_16x16x32_f16(af[kt], bwh[1][kt], z1, 0, 0, 0);
            z2 = __builtin_amdgcn_mfma_f32_16x16x32_f16(af[kt], bwh[2][kt], z2, 0, 0, 0);
            z3 = __builtin_amdgcn_mfma_f32_16x16x32_f16(af[kt], bwh[3][kt], z3, 0, 0, 0);
        }

        // cell update (4 cells/lane, all gates lane-local)
        _Float16* hw = (t & 1) ? hw0 : hw1;   // write into NEXT buffer
        #pragma unroll
        for (int g = 0; g < 4; ++g) {
            const float iv = rcpf(1.0f + ex2(fmaf(z0[g], NLOG2E, nbi)));
            const float fv = rcpf(1.0f + ex2(fmaf(z1[g], NLOG2E, nbf)));
            const float gv = 2.0f * rcpf(1.0f + ex2(fmaf(z2[g], 2.0f * NLOG2E, nbg))) - 1.0f;
            const float ov = rcpf(1.0f + ex2(fmaf(z3[g], NLOG2E, nbo)));
            const float cn = fv * cst[g] + iv * gv;
            cst[g] = cn;
            const float th = 2.0f * rcpf(1.0f + ex2(cn * (2.0f * NLOG2E))) - 1.0f;
            hlast[g] = ov * th;
            hw[g * 8] = (_Float16)hlast[g];   // ds_write_b16, offset g*16B
        }

        xc0 = xn0; xc1 = xn1; xc2 = xn2; xc3 = xn3;
        __syncthreads();
    }

    // final hidden to LDS for heads
    #pragma unroll
    for (int g = 0; g < 4; ++g) xf[(q << 2) + g][ncol] = hlast[g];
    __syncthreads();

    // ---- MLP heads ----
    const int n  = tid & 255;
    const int rh = tid >> 8;
    auto tanhl = [&](float x) { return 2.0f * rcpf(1.0f + ex2(x * (2.0f * NLOG2E))) - 1.0f; };

    auto layer = [&](const float* __restrict__ W, const float* __restrict__ bv,
                     const float* xin, int xs, int K, float* yout, int ys) {
        float acc[8];
        const float b = bv[n];
        #pragma unroll
        for (int r = 0; r < 8; ++r) acc[r] = b;
        #pragma unroll 4
        for (int k = 0; k < K; ++k) {
            const float w = W[k * 256 + n];
            #pragma unroll
            for (int r = 0; r < 8; ++r) acc[r] += xin[(rh * 8 + r) * xs + k] * w;
        }
        #pragma unroll
        for (int r = 0; r < 8; ++r) yout[(rh * 8 + r) * ys + n] = tanhl(acc[r]);
    };

    layer(Wa1, ba1, &xf[0][0], F + 1, 128, &hb[0][0][0], 257);
    __syncthreads();
    layer(Wa2, ba2, &hb[0][0][0], 257, 256, &hb[1][0][0], 257);
    __syncthreads();
    layer(Wc1, bc1, &xf[0][0], F + 1, 128, &hb[0][0][0], 257);
    if (tid < 128) {
        const int r = tid >> 3, aa = tid & 7;
        float acc = ba3[aa];
        #pragma unroll 4
        for (int k = 0; k < 256; ++k) acc += hb[1][r][k] * Wa3[k * 8 + aa];
        out[(size_t)(r0 + r) * 17 + aa]     = acc;
        out[(size_t)(r0 + r) * 17 + 8 + aa] = __expf(logstd[aa]);
    }
    __syncthreads();
    layer(Wc2, bc2, &hb[0][0][0], 257, 256, &hb[1][0][0], 257);
    __syncthreads();
    if (tid < 16) {
        const int r = tid;
        float acc = bc3[0];
        #pragma unroll 4
        for (int k = 0; k < 256; ++k) acc += hb[1][r][k] * Wc3[k];
        out[(size_t)(r0 + r) * 17 + 16] = acc;
    }
}

// ==================== fallback: R3 monolithic kernel =======================
__global__ __launch_bounds__(512, 2)
void ac_fused(const float* __restrict__ hin,
              const float* __restrict__ Wx, const float* __restrict__ Wh,
              const float* __restrict__ bh,
              const float* __restrict__ Wa1, const float* __restrict__ ba1,
              const float* __restrict__ Wa2, const float* __restrict__ ba2,
              const float* __restrict__ Wa3, const float* __restrict__ ba3,
              const float* __restrict__ logstd,
              const float* __restrict__ Wc1, const float* __restrict__ bc1,
              const float* __restrict__ Wc2, const float* __restrict__ bc2,
              const float* __restrict__ Wc3, const float* __restrict__ bc3,
              float* __restrict__ out)
{
    constexpr int T = 256, F = 128, H = 128, G = 512;

    __shared__ f16x8 Abuf[2][512];
    __shared__ float xf[16][F + 1];
    __shared__ float hb[2][16][257];

    const int tid  = threadIdx.x;
    const int lane = tid & 63;
    const int wv   = tid >> 6;
    const int m16  = lane & 15;
    const int q    = lane >> 4;
    const int p    = lane & 1;
    const int r0   = blockIdx.x << 4;

    f16x8 bw[4][8];
    const int ncol = (wv << 4) + m16;
    #pragma unroll
    for (int kt = 0; kt < 8; ++kt) {
        #pragma unroll
        for (int s = 0; s < 4; ++s) {
            f16x8 v;
            #pragma unroll
            for (int j = 0; j < 8; ++j) {
                const int k = (kt << 5) + (q << 3) + j;
                const float w = (k < F) ? Wx[k * G + s * H + ncol]
                                        : Wh[(k - F) * G + s * H + ncol];
                v[j] = (_Float16)w;
            }
            bw[s][kt] = v;
        }
    }
    const float nbi = NLOG2E * bh[0 * H + ncol];
    const float nbf = NLOG2E * bh[1 * H + ncol];
    const float nbg = 2.0f * NLOG2E * bh[2 * H + ncol];
    const float nbo = NLOG2E * bh[3 * H + ncol];

    const int xc = tid >> 1;
    const int xh = tid & 1;
    const int xm = xc & 15;
    const int xk0 = ((xc >> 6) << 5) + (((xc >> 4) & 3) << 3) + (xh << 2);
    const float* pxbase = hin + (size_t)(r0 + xm) * T * F + xk0;

    const int dimc = (wv << 4) + m16;
    const int kk   = F + dimc;
    const int hchunk = ((kk >> 5) << 6) + (((kk >> 3) & 3) << 4);
    const int a    = (m16 & 7) >> 1;
    const int widx0 = (hchunk + (q << 2) + (p << 1)) * 4 + a;
    const int widx1 = widx0 + 4;

    {
        const float4 x0 = *(const float4*)pxbase;
        f16x4 pk;
        pk[0] = (_Float16)x0.x; pk[1] = (_Float16)x0.y;
        pk[2] = (_Float16)x0.z; pk[3] = (_Float16)x0.w;
        *(f16x4*)((_Float16*)&Abuf[0][0] + xc * 8 + xh * 4) = pk;
        f16x4 zz = {};
        *(f16x4*)((_Float16*)&Abuf[0][0] + (256 + xc) * 8 + xh * 4) = zz;
    }

    f32x4 cst = {0.f, 0.f, 0.f, 0.f};
    f32x4 hlast;

    __syncthreads();

    for (int t = 0; t < T; ++t) {
        const int tp = (t + 1 < T) ? t + 1 : T - 1;
        const float4 xn = *(const float4*)(pxbase + (size_t)tp * F);

        const f16x8* Ab = &Abuf[t & 1][0];
        f32x4 z0 = {0.f, 0.f, 0.f, 0.f};
        f32x4 z1 = {0.f, 0.f, 0.f, 0.f};
        f32x4 z2 = {0.f, 0.f, 0.f, 0.f};
        f32x4 z3 = {0.f, 0.f, 0.f, 0.f};
        #pragma unroll
        for (int kt = 0; kt < 8; ++kt) {
            const f16x8 af = Ab[(kt << 6) + lane];
            z0 = __builtin_amdgcn_mfma_f32_16x16x32_f16(af, bw[0][kt], z0, 0, 0, 0);
            z1 = __builtin_amdgcn_mfma_f32_16x16x32_f16(af, bw[1][kt], z1, 0, 0, 0);
            z2 = __builtin_amdgcn_mfma_f32_16x16x32_f16(af, bw[2][kt], z2, 0, 0, 0);
            z3 = __builtin_amdgcn_mfma_f32_16x16x32_f16(af, bw[3][kt], z3, 0, 0, 0);
        }

        #pragma unroll
        for (int g = 0; g < 4; ++g) {
            const float iv = rcpf(1.0f + ex2(fmaf(z0[g], NLOG2E, nbi)));
            const float fv = rcpf(1.0f + ex2(fmaf(z1[g], NLOG2E, nbf)));
            const float gv = 2.0f * rcpf(1.0f + ex2(fmaf(z2[g], 2.0f * NLOG2E, nbg))) - 1.0f;
            const float ov = rcpf(1.0f + ex2(fmaf(z3[g], NLOG2E, nbo)));
            const float cn = fv * cst[g] + iv * gv;
            cst[g] = cn;
            const float th = 2.0f * rcpf(1.0f + ex2(cn * (2.0f * NLOG2E))) - 1.0f;
            hlast[g] = ov * th;
        }

        uint32_t* An32 = (uint32_t*)&Abuf[(t + 1) & 1][0];
        uint32_t dd[4];
        #pragma unroll
        for (int g = 0; g < 4; ++g) {
            const float pp = dpp_swap1(hlast[g]);
            const float lo = p ? pp : hlast[g];
            const float hi = p ? hlast[g] : pp;
            dd[g] = __builtin_bit_cast(uint32_t, __builtin_amdgcn_cvt_pkrtz(lo, hi));
        }
        An32[widx0] = p ? dd[2] : dd[0];
        An32[widx1] = p ? dd[3] : dd[1];

        {
            f16x4 pk;
            pk[0] = (_Float16)xn.x; pk[1] = (_Float16)xn.y;
            pk[2] = (_Float16)xn.z; pk[3] = (_Float16)xn.w;
            *(f16x4*)((_Float16*)An32 + xc * 8 + xh * 4) = pk;
        }
        __syncthreads();
    }

    #pragma unroll
    for (int g = 0; g < 4; ++g) xf[(q << 2) + g][dimc] = hlast[g];
    __syncthreads();

    const int n  = tid & 255;
    const int rh = tid >> 8;
    auto tanhl = [&](float x) { return 2.0f * rcpf(1.0f + ex2(x * (2.0f * NLOG2E))) - 1.0f; };

    auto layer = [&](const float* __restrict__ W, const float* __restrict__ bv,
                     const float* xin, int xs, int K, float* yout, int ys) {
        float acc[8];
        const float b = bv[n];
        #pragma unroll
        for (int r = 0; r < 8; ++r) acc[r] = b;
        #pragma unroll 4
        for (int k = 0; k < K; ++k) {
            const float w = W[k * 256 + n];
            #pragma unroll
            for (int r = 0; r < 8; ++r) acc[r] += xin[(rh * 8 + r) * xs + k] * w;
        }
        #pragma unroll
        for (int r = 0; r < 8; ++r) yout[(rh * 8 + r) * ys + n] = tanhl(acc[r]);
    };

    layer(Wa1, ba1, &xf[0][0], F + 1, 128, &hb[0][0][0], 257);
    __syncthreads();
    layer(Wa2, ba2, &hb[0][0][0], 257, 256, &hb[1][0][0], 257);
    __syncthreads();
    layer(Wc1, bc1, &xf[0][0], F + 1, 128, &hb[0][0][0], 257);
    if (tid < 128) {
        const int r = tid >> 3, aa = tid & 7;
        float acc = ba3[aa];
        #pragma unroll 4
        for (int k = 0; k < 256; ++k) acc += hb[1][r][k] * Wa3[k * 8 + aa];
        out[(size_t)(r0 + r) * 17 + aa]     = acc;
        out[(size_t)(r0 + r) * 17 + 8 + aa] = __expf(logstd[aa]);
    }
    __syncthreads();
    layer(Wc2, bc2, &hb[0][0][0], 257, 256, &hb[1][0][0], 257);
    __syncthreads();
    if (tid < 16) {
        const int r = tid;
        float acc = bc3[0];
        #pragma unroll 4
        for (int k = 0; k < 256; ++k) acc += hb[1][r][k] * Wc3[k];
        out[(size_t)(r0 + r) * 17 + 16] = acc;
    }
}

extern "C" void kernel_launch(void* const* d_in, const int* in_sizes, int n_in,
                              void* d_out, int out_size, void* d_ws, size_t ws_size,
                              hipStream_t stream) {
    (void)in_sizes; (void)n_in; (void)out_size;
    const float* hin = (const float*)d_in[0];
    const float* Wx  = (const float*)d_in[1];
    const float* Wh  = (const float*)d_in[2];
    const float* bh  = (const float*)d_in[3];
    const float* Wa1 = (const float*)d_in[4];
    const float* ba1 = (const float*)d_in[5];
    const float* Wa2 = (const float*)d_in[6];
    const float* ba2 = (const float*)d_in[7];
    const float* Wa3 = (const float*)d_in[8];
    const float* ba3 = (const float*)d_in[9];
    const float* ls  = (const float*)d_in[10];
    const float* Wc1 = (const float*)d_in[11];
    const float* bc1 = (const float*)d_in[12];
    const float* Wc2 = (const float*)d_in[13];
    const float* bc2 = (const float*)d_in[14];
    const float* Wc3 = (const float*)d_in[15];
    const float* bc3 = (const float*)d_in[16];

    const size_t XG_BYTES = (size_t)256 * 1024 * 1024;  // B*T*4H f16
    if (ws_size >= XG_BYTES) {
        _Float16* xg = (_Float16*)d_ws;
        hipLaunchKernelGGL(xg_gemm, dim3(512), dim3(512), 0, stream, hin, Wx, xg);
        hipLaunchKernelGGL(ac_scan, dim3(64), dim3(512), 0, stream,
                           xg, Wh, bh, Wa1, ba1, Wa2, ba2, Wa3, ba3, ls,
                           Wc1, bc1, Wc2, bc2, Wc3, bc3, (float*)d_out);
    } else {
        hipLaunchKernelGGL(ac_fused, dim3(64), dim3(512), 0, stream,
                           hin, Wx, Wh, bh, Wa1, ba1, Wa2, ba2, Wa3, ba3, ls,
                           Wc1, bc1, Wc2, bc2, Wc3, bc3, (float*)d_out);
    }
}